// Round 8
// baseline (118.275 us; speedup 1.0000x reference)
//
#include <hip/hip_runtime.h>
#include <math.h>

// Fused ConvTranspose2d(64->64,k4,s2,p1) + MaxPool2x2 + Hardtanh + mean + tanh
// via bf16 MFMA implicit GEMM. Quad/tap decomposition verified exact (round 1).
//
// MFMA 16x16x32 bf16: A lane l: row=l&15, k=(l>>4)*8+j ; B same with col;
//                     C lane l: col=l&15, row=(l>>4)*4+j   [HW-verified m89]
//
// Round-8 change: A-reuse x2. 256-thread blocks (4 waves); wave = 2 sequential
// pooled rows x 64 px x 32 co (n=2 co-tiles). Each A-fragment ds_read now
// feeds 2 MFMAs instead of 1 -> per-CU LDS A-reads halve (1152 -> 576,
// ~15us -> ~6us LDS pipe). acc[4][4][2] = 128 VGPR; __launch_bounds__(256,2)
// = min 2 waves/EU -> 256-VGPR budget (usage ~185, no spill expected;
// WRITE_SIZE is the falsifier).
// History: R4 = no per-block agent-scope fences (~100us all-pipes-idle stall).
// R3/R4 = spills show up as WRITE_SIZE tens-of-MB.

typedef __attribute__((ext_vector_type(8))) short short8;
typedef __attribute__((ext_vector_type(4))) float f32x4;

#define XS_ROW 66
#define XS_CI 72          // halfwords per (row,iw) slot: 64 ci + 8 pad
#define XS_CI_U32 36

__device__ __forceinline__ unsigned short f2bf(float f) {
    unsigned int u = __builtin_bit_cast(unsigned int, f);
    u += 0x7fffu + ((u >> 16) & 1u);   // round-to-nearest-even
    return (unsigned short)(u >> 16);
}

// ---------------------------------------------------------------------------
// Weight prep (coalesced reads): read w[ci][co][16] as float4, scatter bf16
// into B-fragment layout: hw idx = (((qt*4 + n)*2 + kb2)*64 + lane)*8 + j
//   ci = kb2*32 + (lane>>4)*8 + j, co = n*16 + (lane&15), (kh,kw) = f(qt).
// Also zeroes partial[2048]. 256 blocks x 64 threads = 1 wave on every CU.
// ---------------------------------------------------------------------------
__global__ void wprep_kernel(const float* __restrict__ w,
                             unsigned short* __restrict__ wsB,
                             float* __restrict__ partial)
{
    const int g = blockIdx.x * 64 + threadIdx.x;   // 0..16383
    const int ci  = g >> 8;
    const int co  = (g >> 2) & 63;
    const int kkq = g & 3;

    const float4 v = *(const float4*)(w + (size_t)ci * 1024 + (size_t)co * 16 + kkq * 4);
    const float vv[4] = {v.x, v.y, v.z, v.w};

    const int n    = co >> 4;
    const int kb2  = ci >> 5;
    const int lane = ((ci >> 3) & 3) * 16 + (co & 15);
    const int j    = ci & 7;

    // inverse of the forward (q,t)->(kh,kw) map
    constexpr int H2Q[4] = {1, 0, 1, 0};
    constexpr int H2T[4] = {1, 0, 0, 1};

    #pragma unroll
    for (int j4 = 0; j4 < 4; ++j4) {
        const int kk = kkq * 4 + j4;
        const int kh = kk >> 2, kw = kk & 3;
        const int q  = H2Q[kh] * 2 + H2Q[kw];
        const int t  = H2T[kh] * 2 + H2T[kw];
        const int qt = q * 4 + t;
        const size_t idx = ((((size_t)(qt * 4 + n)) * 2 + kb2) * 64 + lane) * 8 + j;
        wsB[idx] = f2bf(vv[j4]);
    }
    if (g < 2048) partial[g] = 0.f;
}

// ---------------------------------------------------------------------------
// Main kernel: 512 blocks x 256 threads (4 waves), 2 blocks/CU resident.
// Block = (batch b, pooled-row-quad rp4): pooled rows 4*rp4 .. 4*rp4+3.
// LDS tile: input rows 4*rp4-1 .. 4*rp4+4 (6 rows), iw -1..64, 64 ci bf16.
// Wave wv: rr = wv>>1 -> pooled rows {2rr, 2rr+1} (sequential), ch2 = wv&1
// (32-co half). Per row: tap-major, m = 4 px tiles x n = 2 co tiles.
// ---------------------------------------------------------------------------
__global__ __launch_bounds__(256, 2) void convt_mfma_kernel(
    const float* __restrict__ x,           // [32][64][64][64]
    const float* __restrict__ bias,        // [64]
    const unsigned short* __restrict__ wsB,
    float* __restrict__ partial)           // [2048]
{
    __shared__ __align__(16) unsigned int xs[6 * XS_ROW * XS_CI_U32];  // 57024 B

    const int wg  = blockIdx.x;       // 0..511
    const int xcd = wg & 7;
    const int k   = wg >> 3;          // 0..63
    const int b   = xcd * 4 + (k >> 4);
    const int rp4 = k & 15;
    const int ph0 = rp4 * 4;          // first pooled row of this block
    const int tid = threadIdx.x;

    // ---- stage x tile: input rows ph0-1 .. ph0+4, iw -1..64, 64 ci ----
    {
        const int iw   = tid & 63;
        const int part = tid >> 6;    // 0..3 : ci block of 16
        #pragma unroll
        for (int r6 = 0; r6 < 6; ++r6) {
            const int  ih    = ph0 - 1 + r6;
            const bool rowok = ((unsigned)ih < 64u);
            unsigned int pk[8];
            #pragma unroll
            for (int h = 0; h < 8; ++h) {
                const int ci = part * 16 + h * 2;
                float v0 = 0.f, v1 = 0.f;
                if (rowok) {
                    const size_t base = (((size_t)(b * 64 + ci)) * 64 + ih) * 64 + iw;
                    v0 = x[base];
                    v1 = x[base + 4096];
                }
                pk[h] = (unsigned)f2bf(v0) | ((unsigned)f2bf(v1) << 16);
            }
            unsigned int* dst = &xs[(r6 * XS_ROW + iw + 1) * XS_CI_U32 + part * 8];
            *(uint4*)(dst)     = make_uint4(pk[0], pk[1], pk[2], pk[3]);
            *(uint4*)(dst + 4) = make_uint4(pk[4], pk[5], pk[6], pk[7]);
            if (iw == 0 || iw == 63) {
                const int slot = (iw == 0) ? 0 : 65;
                unsigned int* zp = &xs[(r6 * XS_ROW + slot) * XS_CI_U32 + part * 8];
                *(uint4*)(zp)     = make_uint4(0u, 0u, 0u, 0u);
                *(uint4*)(zp + 4) = make_uint4(0u, 0u, 0u, 0u);
            }
        }
    }
    __syncthreads();

    const int wv   = tid >> 6;        // 0..3
    const int rr   = wv >> 1;         // row-pair within block
    const int ch2  = wv & 1;          // co half (32 co)
    const int lane = tid & 63;
    const int p    = lane & 15;
    const int hi   = lane >> 4;

    const unsigned short* xs16 = (const unsigned short*)xs;
    const unsigned short* wB = wsB + (size_t)lane * 8;

    // 9 distinct taps; quad q uses tap (dh,dw) iff rows_ok && cols_ok:
    //   dh: -1 -> q<2, 0 -> all, 1 -> q>=2 ; dw: -1 -> q even, 0 -> all, 1 -> q odd
    // t within q: t = 2*(dh!=0) + (dw!=0); qt = q*4+t.
    constexpr int TDH[9] = {-1,-1,-1,  0, 0, 0,  1, 1, 1};
    constexpr int TDW[9] = {-1, 0, 1, -1, 0, 1, -1, 0, 1};

    float s[2] = {0.f, 0.f};
    const float bv0 = bias[ch2 * 32 + p];
    const float bv1 = bias[ch2 * 32 + 16 + p];

    #pragma unroll
    for (int pr = 0; pr < 2; ++pr) {
        const int prow  = rr * 2 + pr;   // block-relative pooled row 0..3
        const int abase = ((prow + 1) * XS_ROW + (p + 1)) * XS_CI + hi * 8;

        f32x4 acc[4][4][2];   // [m][q][n] = 128 VGPR
        #pragma unroll
        for (int m = 0; m < 4; ++m)
            #pragma unroll
            for (int q = 0; q < 4; ++q)
                #pragma unroll
                for (int n = 0; n < 2; ++n)
                    acc[m][q][n] = (f32x4){0.f, 0.f, 0.f, 0.f};

        #pragma unroll
        for (int tp = 0; tp < 9; ++tp) {
            const int dh = TDH[tp], dw = TDW[tp];
            const int t  = 2 * (dh != 0) + (dw != 0);
            #pragma unroll
            for (int kb2 = 0; kb2 < 2; ++kb2) {
                short8 Af[4];
                const int ao = abase + dh * (XS_ROW * XS_CI) + dw * XS_CI + kb2 * 32;
                #pragma unroll
                for (int m = 0; m < 4; ++m)
                    Af[m] = *(const short8*)(xs16 + ao + m * (16 * XS_CI));

                #pragma unroll
                for (int q = 0; q < 4; ++q) {
                    const bool rows_ok = (dh == 0) || (dh == -1 ? (q < 2) : (q >= 2));
                    const bool cols_ok = (dw == 0) || (dw == -1 ? ((q & 1) == 0)
                                                                : ((q & 1) == 1));
                    if (rows_ok && cols_ok) {
                        const int qt = q * 4 + t;
                        #pragma unroll
                        for (int n = 0; n < 2; ++n) {
                            const short8 Bf = *(const short8*)(
                                wB + (((size_t)(qt * 4 + ch2 * 2 + n) * 2 + kb2) << 9));
                            #pragma unroll
                            for (int m = 0; m < 4; ++m)
                                acc[m][q][n] = __builtin_amdgcn_mfma_f32_16x16x32_bf16(
                                    Af[m], Bf, acc[m][q][n], 0, 0, 0);
                        }
                    }
                }
            }
        }

        // max over quads + bias + hardtanh + accumulate this row's 64 px
        #pragma unroll
        for (int n = 0; n < 2; ++n) {
            const float bv = (n == 0) ? bv0 : bv1;
            #pragma unroll
            for (int m = 0; m < 4; ++m)
                #pragma unroll
                for (int j = 0; j < 4; ++j) {
                    const float vm = fmaxf(fmaxf(acc[m][0][n][j], acc[m][1][n][j]),
                                           fmaxf(acc[m][2][n][j], acc[m][3][n][j]));
                    float v = vm + bv;
                    v = fminf(fmaxf(v, -1.f), 1.f);
                    s[n] += v;
                }
        }
    }

    #pragma unroll
    for (int n = 0; n < 2; ++n) {
        float v = s[n];
        v += __shfl_xor(v, 16, 64);
        v += __shfl_xor(v, 32, 64);
        if (hi == 0) atomicAdd(&partial[b * 64 + ch2 * 32 + n * 16 + p], v);
    }
}

__global__ void finalize_kernel(const float* __restrict__ partial, float* __restrict__ out)
{
    const int i = blockIdx.x * blockDim.x + threadIdx.x;
    if (i < 2048) out[i] = tanhf(partial[i] * (1.0f / 4096.0f));
}

extern "C" void kernel_launch(void* const* d_in, const int* in_sizes, int n_in,
                              void* d_out, int out_size, void* d_ws, size_t ws_size,
                              hipStream_t stream)
{
    (void)in_sizes; (void)n_in; (void)out_size; (void)ws_size;
    const float* x  = (const float*)d_in[0];
    const float* w  = (const float*)d_in[1];
    const float* bi = (const float*)d_in[2];
    float* out = (float*)d_out;

    unsigned short* wsB     = (unsigned short*)d_ws;           // 131072 B
    float*          partial = (float*)((char*)d_ws + 131072);  // 8192 B

    wprep_kernel<<<256, 64, 0, stream>>>(w, wsB, partial);
    convt_mfma_kernel<<<512, 256, 0, stream>>>(x, bi, wsB, partial);
    finalize_kernel<<<8, 256, 0, stream>>>(partial, out);
}

// Round 9
// 103.113 us; speedup vs baseline: 1.1470x; 1.1470x over previous
//
#include <hip/hip_runtime.h>
#include <math.h>

// Fused ConvTranspose2d(64->64,k4,s2,p1) + MaxPool2x2 + Hardtanh + mean + tanh
// via bf16 MFMA implicit GEMM. Quad/tap decomposition verified exact (round 1).
//
// MFMA 16x16x32 bf16: A lane l: row=l&15, k=(l>>4)*8+j ; B same with col;
//                     C lane l: col=l&15, row=(l>>4)*4+j   [HW-verified m89]
//
// Round-9 change: ONLY __launch_bounds__(256, 2) -> (256, 1).
// Empirical allocator rule from R2/R3/R4/R8: VGPR cap = 256 / arg2 (block
// size irrelevant). R8's n=2 A-reuse design needs ~190 live VGPRs; under
// arg2=2 (cap 128) it spilled 81 MB (WRITE_SIZE) and ran 48 us. arg2=1 gives
// the 256-reg budget -> 2 waves/SIMD, 2 blocks/CU, 512-block grid = one
// residency round.
// History: R4 = no per-block agent-scope fences (~100us all-pipes-idle stall).
// Spills show up as WRITE_SIZE tens-of-MB (R2/R3/R8).

typedef __attribute__((ext_vector_type(8))) short short8;
typedef __attribute__((ext_vector_type(4))) float f32x4;

#define XS_ROW 66
#define XS_CI 72          // halfwords per (row,iw) slot: 64 ci + 8 pad
#define XS_CI_U32 36

__device__ __forceinline__ unsigned short f2bf(float f) {
    unsigned int u = __builtin_bit_cast(unsigned int, f);
    u += 0x7fffu + ((u >> 16) & 1u);   // round-to-nearest-even
    return (unsigned short)(u >> 16);
}

// ---------------------------------------------------------------------------
// Weight prep (coalesced reads): read w[ci][co][16] as float4, scatter bf16
// into B-fragment layout: hw idx = (((qt*4 + n)*2 + kb2)*64 + lane)*8 + j
//   ci = kb2*32 + (lane>>4)*8 + j, co = n*16 + (lane&15), (kh,kw) = f(qt).
// Also zeroes partial[2048]. 256 blocks x 64 threads = 1 wave on every CU.
// ---------------------------------------------------------------------------
__global__ void wprep_kernel(const float* __restrict__ w,
                             unsigned short* __restrict__ wsB,
                             float* __restrict__ partial)
{
    const int g = blockIdx.x * 64 + threadIdx.x;   // 0..16383
    const int ci  = g >> 8;
    const int co  = (g >> 2) & 63;
    const int kkq = g & 3;

    const float4 v = *(const float4*)(w + (size_t)ci * 1024 + (size_t)co * 16 + kkq * 4);
    const float vv[4] = {v.x, v.y, v.z, v.w};

    const int n    = co >> 4;
    const int kb2  = ci >> 5;
    const int lane = ((ci >> 3) & 3) * 16 + (co & 15);
    const int j    = ci & 7;

    // inverse of the forward (q,t)->(kh,kw) map
    constexpr int H2Q[4] = {1, 0, 1, 0};
    constexpr int H2T[4] = {1, 0, 0, 1};

    #pragma unroll
    for (int j4 = 0; j4 < 4; ++j4) {
        const int kk = kkq * 4 + j4;
        const int kh = kk >> 2, kw = kk & 3;
        const int q  = H2Q[kh] * 2 + H2Q[kw];
        const int t  = H2T[kh] * 2 + H2T[kw];
        const int qt = q * 4 + t;
        const size_t idx = ((((size_t)(qt * 4 + n)) * 2 + kb2) * 64 + lane) * 8 + j;
        wsB[idx] = f2bf(vv[j4]);
    }
    if (g < 2048) partial[g] = 0.f;
}

// ---------------------------------------------------------------------------
// Main kernel: 512 blocks x 256 threads (4 waves), 2 blocks/CU resident.
// Block = (batch b, pooled-row-quad rp4): pooled rows 4*rp4 .. 4*rp4+3.
// LDS tile: input rows 4*rp4-1 .. 4*rp4+4 (6 rows), iw -1..64, 64 ci bf16.
// Wave wv: rr = wv>>1 -> pooled rows {2rr, 2rr+1} (sequential), ch2 = wv&1
// (32-co half). Per row: tap-major, m = 4 px tiles x n = 2 co tiles.
// ---------------------------------------------------------------------------
__global__ __launch_bounds__(256, 1) void convt_mfma_kernel(
    const float* __restrict__ x,           // [32][64][64][64]
    const float* __restrict__ bias,        // [64]
    const unsigned short* __restrict__ wsB,
    float* __restrict__ partial)           // [2048]
{
    __shared__ __align__(16) unsigned int xs[6 * XS_ROW * XS_CI_U32];  // 57024 B

    const int wg  = blockIdx.x;       // 0..511
    const int xcd = wg & 7;
    const int k   = wg >> 3;          // 0..63
    const int b   = xcd * 4 + (k >> 4);
    const int rp4 = k & 15;
    const int ph0 = rp4 * 4;          // first pooled row of this block
    const int tid = threadIdx.x;

    // ---- stage x tile: input rows ph0-1 .. ph0+4, iw -1..64, 64 ci ----
    {
        const int iw   = tid & 63;
        const int part = tid >> 6;    // 0..3 : ci block of 16
        #pragma unroll
        for (int r6 = 0; r6 < 6; ++r6) {
            const int  ih    = ph0 - 1 + r6;
            const bool rowok = ((unsigned)ih < 64u);
            unsigned int pk[8];
            #pragma unroll
            for (int h = 0; h < 8; ++h) {
                const int ci = part * 16 + h * 2;
                float v0 = 0.f, v1 = 0.f;
                if (rowok) {
                    const size_t base = (((size_t)(b * 64 + ci)) * 64 + ih) * 64 + iw;
                    v0 = x[base];
                    v1 = x[base + 4096];
                }
                pk[h] = (unsigned)f2bf(v0) | ((unsigned)f2bf(v1) << 16);
            }
            unsigned int* dst = &xs[(r6 * XS_ROW + iw + 1) * XS_CI_U32 + part * 8];
            *(uint4*)(dst)     = make_uint4(pk[0], pk[1], pk[2], pk[3]);
            *(uint4*)(dst + 4) = make_uint4(pk[4], pk[5], pk[6], pk[7]);
            if (iw == 0 || iw == 63) {
                const int slot = (iw == 0) ? 0 : 65;
                unsigned int* zp = &xs[(r6 * XS_ROW + slot) * XS_CI_U32 + part * 8];
                *(uint4*)(zp)     = make_uint4(0u, 0u, 0u, 0u);
                *(uint4*)(zp + 4) = make_uint4(0u, 0u, 0u, 0u);
            }
        }
    }
    __syncthreads();

    const int wv   = tid >> 6;        // 0..3
    const int rr   = wv >> 1;         // row-pair within block
    const int ch2  = wv & 1;          // co half (32 co)
    const int lane = tid & 63;
    const int p    = lane & 15;
    const int hi   = lane >> 4;

    const unsigned short* xs16 = (const unsigned short*)xs;
    const unsigned short* wB = wsB + (size_t)lane * 8;

    // 9 distinct taps; quad q uses tap (dh,dw) iff rows_ok && cols_ok:
    //   dh: -1 -> q<2, 0 -> all, 1 -> q>=2 ; dw: -1 -> q even, 0 -> all, 1 -> q odd
    // t within q: t = 2*(dh!=0) + (dw!=0); qt = q*4+t.
    constexpr int TDH[9] = {-1,-1,-1,  0, 0, 0,  1, 1, 1};
    constexpr int TDW[9] = {-1, 0, 1, -1, 0, 1, -1, 0, 1};

    float s[2] = {0.f, 0.f};
    const float bv0 = bias[ch2 * 32 + p];
    const float bv1 = bias[ch2 * 32 + 16 + p];

    #pragma unroll
    for (int pr = 0; pr < 2; ++pr) {
        const int prow  = rr * 2 + pr;   // block-relative pooled row 0..3
        const int abase = ((prow + 1) * XS_ROW + (p + 1)) * XS_CI + hi * 8;

        f32x4 acc[4][4][2];   // [m][q][n] = 128 VGPR
        #pragma unroll
        for (int m = 0; m < 4; ++m)
            #pragma unroll
            for (int q = 0; q < 4; ++q)
                #pragma unroll
                for (int n = 0; n < 2; ++n)
                    acc[m][q][n] = (f32x4){0.f, 0.f, 0.f, 0.f};

        #pragma unroll
        for (int tp = 0; tp < 9; ++tp) {
            const int dh = TDH[tp], dw = TDW[tp];
            const int t  = 2 * (dh != 0) + (dw != 0);
            #pragma unroll
            for (int kb2 = 0; kb2 < 2; ++kb2) {
                short8 Af[4];
                const int ao = abase + dh * (XS_ROW * XS_CI) + dw * XS_CI + kb2 * 32;
                #pragma unroll
                for (int m = 0; m < 4; ++m)
                    Af[m] = *(const short8*)(xs16 + ao + m * (16 * XS_CI));

                #pragma unroll
                for (int q = 0; q < 4; ++q) {
                    const bool rows_ok = (dh == 0) || (dh == -1 ? (q < 2) : (q >= 2));
                    const bool cols_ok = (dw == 0) || (dw == -1 ? ((q & 1) == 0)
                                                                : ((q & 1) == 1));
                    if (rows_ok && cols_ok) {
                        const int qt = q * 4 + t;
                        #pragma unroll
                        for (int n = 0; n < 2; ++n) {
                            const short8 Bf = *(const short8*)(
                                wB + (((size_t)(qt * 4 + ch2 * 2 + n) * 2 + kb2) << 9));
                            #pragma unroll
                            for (int m = 0; m < 4; ++m)
                                acc[m][q][n] = __builtin_amdgcn_mfma_f32_16x16x32_bf16(
                                    Af[m], Bf, acc[m][q][n], 0, 0, 0);
                        }
                    }
                }
            }
        }

        // max over quads + bias + hardtanh + accumulate this row's 64 px
        #pragma unroll
        for (int n = 0; n < 2; ++n) {
            const float bv = (n == 0) ? bv0 : bv1;
            #pragma unroll
            for (int m = 0; m < 4; ++m)
                #pragma unroll
                for (int j = 0; j < 4; ++j) {
                    const float vm = fmaxf(fmaxf(acc[m][0][n][j], acc[m][1][n][j]),
                                           fmaxf(acc[m][2][n][j], acc[m][3][n][j]));
                    float v = vm + bv;
                    v = fminf(fmaxf(v, -1.f), 1.f);
                    s[n] += v;
                }
        }
    }

    #pragma unroll
    for (int n = 0; n < 2; ++n) {
        float v = s[n];
        v += __shfl_xor(v, 16, 64);
        v += __shfl_xor(v, 32, 64);
        if (hi == 0) atomicAdd(&partial[b * 64 + ch2 * 32 + n * 16 + p], v);
    }
}

__global__ void finalize_kernel(const float* __restrict__ partial, float* __restrict__ out)
{
    const int i = blockIdx.x * blockDim.x + threadIdx.x;
    if (i < 2048) out[i] = tanhf(partial[i] * (1.0f / 4096.0f));
}

extern "C" void kernel_launch(void* const* d_in, const int* in_sizes, int n_in,
                              void* d_out, int out_size, void* d_ws, size_t ws_size,
                              hipStream_t stream)
{
    (void)in_sizes; (void)n_in; (void)out_size; (void)ws_size;
    const float* x  = (const float*)d_in[0];
    const float* w  = (const float*)d_in[1];
    const float* bi = (const float*)d_in[2];
    float* out = (float*)d_out;

    unsigned short* wsB     = (unsigned short*)d_ws;           // 131072 B
    float*          partial = (float*)((char*)d_ws + 131072);  // 8192 B

    wprep_kernel<<<256, 64, 0, stream>>>(w, wsB, partial);
    convt_mfma_kernel<<<512, 256, 0, stream>>>(x, bi, wsB, partial);
    finalize_kernel<<<8, 256, 0, stream>>>(partial, out);
}

// Round 10
// 101.487 us; speedup vs baseline: 1.1654x; 1.0160x over previous
//
#include <hip/hip_runtime.h>
#include <math.h>

// Fused ConvTranspose2d(64->64,k4,s2,p1) + MaxPool2x2 + Hardtanh + mean + tanh
// via bf16 MFMA implicit GEMM. Quad/tap decomposition verified exact (round 1).
//
// MFMA 16x16x32 bf16: A lane l: row=l&15, k=(l>>4)*8+j ; B same with col;
//                     C lane l: col=l&15, row=(l>>4)*4+j   [HW-verified m89]
//
// Round-10: QUAD-SPLIT ACROSS WAVE PAIRS. m4xn2 tiling halves both A-LDS
// reads and B-loads vs R7, but acc[4][4][2]=256 VGPR can't fit (R8/R9: spill
// or 2-waves/SIMD occupancy collapse). Quads {0,1} (taps dh in {-1,0}) and
// {2,3} (dh in {0,1}) are independent until the pooling max, and hardtanh is
// monotone (clip(max(a,b)) = max(clip a, clip b)) -> each wave computes one
// quad-half (acc[4][2][2]=64 regs), exchanges CLIPPED bf16 maxima through a
// 17 KB LDS buffer. ~112 regs -> 16 waves/CU.
// History: R4 = no per-block agent-scope fences. R8/R9 = reg estimates run
// ~30 low vs compiler; keep live state <= ~110. Spill falsifier = WRITE_SIZE.

typedef __attribute__((ext_vector_type(8))) short short8;
typedef __attribute__((ext_vector_type(4))) float f32x4;

#define XS_ROW 66
#define XS_CI 72          // halfwords per (row,iw) slot: 64 ci + 8 pad
#define XS_CI_U32 36
#define MB_PX 34          // u32 per co-row of maxbuf (32 px-pairs + 2 pad)

__device__ __forceinline__ unsigned short f2bf(float f) {
    unsigned int u = __builtin_bit_cast(unsigned int, f);
    u += 0x7fffu + ((u >> 16) & 1u);   // round-to-nearest-even
    return (unsigned short)(u >> 16);
}
__device__ __forceinline__ float bf2f_lo(unsigned int u) {
    return __builtin_bit_cast(float, u << 16);
}
__device__ __forceinline__ float bf2f_hi(unsigned int u) {
    return __builtin_bit_cast(float, u & 0xffff0000u);
}

// ---------------------------------------------------------------------------
// Weight prep (unchanged layout from R7/R9): coalesced float4 reads, scatter
// bf16 into B-fragment layout: hw idx = (((qt*4 + n)*2 + kb2)*64 + lane)*8 + j
//   ci = kb2*32 + (lane>>4)*8 + j, co = n*16 + (lane&15), (kh,kw) = f(qt).
// Also zeroes partial[2048].
// ---------------------------------------------------------------------------
__global__ void wprep_kernel(const float* __restrict__ w,
                             unsigned short* __restrict__ wsB,
                             float* __restrict__ partial)
{
    const int g = blockIdx.x * 64 + threadIdx.x;   // 0..16383
    const int ci  = g >> 8;
    const int co  = (g >> 2) & 63;
    const int kkq = g & 3;

    const float4 v = *(const float4*)(w + (size_t)ci * 1024 + (size_t)co * 16 + kkq * 4);
    const float vv[4] = {v.x, v.y, v.z, v.w};

    const int n    = co >> 4;
    const int kb2  = ci >> 5;
    const int lane = ((ci >> 3) & 3) * 16 + (co & 15);
    const int j    = ci & 7;

    constexpr int H2Q[4] = {1, 0, 1, 0};
    constexpr int H2T[4] = {1, 0, 0, 1};

    #pragma unroll
    for (int j4 = 0; j4 < 4; ++j4) {
        const int kk = kkq * 4 + j4;
        const int kh = kk >> 2, kw = kk & 3;
        const int q  = H2Q[kh] * 2 + H2Q[kw];
        const int t  = H2T[kh] * 2 + H2T[kw];
        const int qt = q * 4 + t;
        const size_t idx = ((((size_t)(qt * 4 + n)) * 2 + kb2) * 64 + lane) * 8 + j;
        wsB[idx] = f2bf(vv[j4]);
    }
    if (g < 2048) partial[g] = 0.f;
}

// ---------------------------------------------------------------------------
// One quad-half of one pooled row x 32 co. QH=0 -> quads {0,1} (dh in {-1,0}),
// QH=1 -> quads {2,3} (dh in {0,1}). Produces clipped bf16-packed maxima:
// QH0 writes them to the LDS maxbuf row, QH1 keeps them in ownpk[16].
// Tap->qt mapping re-verified against the R1-exact DHt/DWt table (all 16).
// ---------------------------------------------------------------------------
template<int QH>
__device__ __forceinline__ void compute_half(
    const unsigned short* xs16, const unsigned short* wB,
    const int abase, const int ch2, const int p, const int hi,
    const float bv0, const float bv1,
    unsigned int* mrow, unsigned int* ownpk)
{
    f32x4 acc[4][2][2];   // [m][qq][n] = 64 VGPR
    #pragma unroll
    for (int m = 0; m < 4; ++m)
        #pragma unroll
        for (int qq = 0; qq < 2; ++qq)
            #pragma unroll
            for (int n = 0; n < 2; ++n)
                acc[m][qq][n] = (f32x4){0.f, 0.f, 0.f, 0.f};

    #pragma unroll
    for (int tap = 0; tap < 6; ++tap) {
        const int dh = (tap < 3) ? (QH ? 0 : -1) : (QH ? 1 : 0);
        const int dw = (tap % 3) - 1;
        const int t  = 2 * (dh != 0) + (dw != 0);
        const int ao0 = abase + dh * (XS_ROW * XS_CI) + dw * XS_CI;
        #pragma unroll
        for (int kb2 = 0; kb2 < 2; ++kb2) {
            short8 Bf[2][2];
            #pragma unroll
            for (int qq = 0; qq < 2; ++qq) {
                if ((dw == 0) || ((dw == -1) ? (qq == 0) : (qq == 1))) {
                    const int qt = (QH * 2 + qq) * 4 + t;
                    #pragma unroll
                    for (int n = 0; n < 2; ++n)
                        Bf[qq][n] = *(const short8*)(wB +
                            (((size_t)(qt * 4 + ch2 * 2 + n) * 2 + kb2) << 9));
                }
            }
            #pragma unroll
            for (int mh = 0; mh < 2; ++mh) {
                short8 Af[2];
                #pragma unroll
                for (int i = 0; i < 2; ++i)
                    Af[i] = *(const short8*)(xs16 + ao0 + kb2 * 32 +
                                             (mh * 2 + i) * (16 * XS_CI));
                #pragma unroll
                for (int qq = 0; qq < 2; ++qq) {
                    if ((dw == 0) || ((dw == -1) ? (qq == 0) : (qq == 1))) {
                        #pragma unroll
                        for (int n = 0; n < 2; ++n)
                            #pragma unroll
                            for (int i = 0; i < 2; ++i)
                                acc[mh * 2 + i][qq][n] =
                                    __builtin_amdgcn_mfma_f32_16x16x32_bf16(
                                        Af[i], Bf[qq][n], acc[mh * 2 + i][qq][n],
                                        0, 0, 0);
                    }
                }
            }
        }
    }

    // clipped max over this wave's 2 quads, packed to bf16 pairs
    #pragma unroll
    for (int m = 0; m < 4; ++m)
        #pragma unroll
        for (int n = 0; n < 2; ++n) {
            const float bvn = n ? bv1 : bv0;
            float v0 = fminf(fmaxf(fmaxf(acc[m][0][n][0], acc[m][1][n][0]) + bvn, -1.f), 1.f);
            float v1 = fminf(fmaxf(fmaxf(acc[m][0][n][1], acc[m][1][n][1]) + bvn, -1.f), 1.f);
            float v2 = fminf(fmaxf(fmaxf(acc[m][0][n][2], acc[m][1][n][2]) + bvn, -1.f), 1.f);
            float v3 = fminf(fmaxf(fmaxf(acc[m][0][n][3], acc[m][1][n][3]) + bvn, -1.f), 1.f);
            const unsigned int w0 = (unsigned)f2bf(v0) | ((unsigned)f2bf(v1) << 16);
            const unsigned int w1 = (unsigned)f2bf(v2) | ((unsigned)f2bf(v3) << 16);
            if (QH == 0) {
                uint2 pk; pk.x = w0; pk.y = w1;
                *(uint2*)(mrow + (n * 16 + p) * MB_PX + m * 8 + hi * 2) = pk;
            } else {
                ownpk[(m * 2 + n) * 2 + 0] = w0;
                ownpk[(m * 2 + n) * 2 + 1] = w1;
            }
        }
}

// ---------------------------------------------------------------------------
// Main kernel: 512 blocks x 512 threads (8 waves), 2 blocks/CU.
// Block = (batch b, pooled-row-quad rp4); 6-input-row LDS tile (57 KB).
// Wave wv: qh = wv>>2 (quad-half), row2 = (wv>>1)&1, ch2 = wv&1 (32-co half).
// 2 rounds: pooled rows {0,1} then {2,3} of the block; maxbuf reused.
// ---------------------------------------------------------------------------
__global__ __launch_bounds__(512, 2) void convt_mfma_kernel(
    const float* __restrict__ x,           // [32][64][64][64]
    const float* __restrict__ bias,        // [64]
    const unsigned short* __restrict__ wsB,
    float* __restrict__ partial)           // [2048]
{
    __shared__ __align__(16) unsigned int xs[6 * XS_ROW * XS_CI_U32];  // 57024 B
    __shared__ __align__(16) unsigned int maxbuf[2][2][32][MB_PX];     // 17408 B

    const int wg  = blockIdx.x;       // 0..511
    const int xcd = wg & 7;
    const int k   = wg >> 3;          // 0..63
    const int b   = xcd * 4 + (k >> 4);
    const int rp4 = k & 15;
    const int ph0 = rp4 * 4;          // first pooled row of this block
    const int tid = threadIdx.x;

    // ---- stage x tile: input rows ph0-1 .. ph0+4, iw -1..64, 64 ci ----
    {
        const int iw   = tid & 63;
        const int part = tid >> 6;    // 0..7 : ci block of 8
        #pragma unroll
        for (int r6 = 0; r6 < 6; ++r6) {
            const int  ih    = ph0 - 1 + r6;
            const bool rowok = ((unsigned)ih < 64u);
            unsigned int pk[4];
            #pragma unroll
            for (int h = 0; h < 4; ++h) {
                const int ci = part * 8 + h * 2;
                float v0 = 0.f, v1 = 0.f;
                if (rowok) {
                    const size_t base = (((size_t)(b * 64 + ci)) * 64 + ih) * 64 + iw;
                    v0 = x[base];
                    v1 = x[base + 4096];
                }
                pk[h] = (unsigned)f2bf(v0) | ((unsigned)f2bf(v1) << 16);
            }
            unsigned int* dst = &xs[(r6 * XS_ROW + iw + 1) * XS_CI_U32 + part * 4];
            *(uint4*)(dst) = make_uint4(pk[0], pk[1], pk[2], pk[3]);
            if (iw == 0 || iw == 63) {
                const int slot = (iw == 0) ? 0 : 65;
                unsigned int* zp = &xs[(r6 * XS_ROW + slot) * XS_CI_U32 + part * 4];
                *(uint4*)(zp) = make_uint4(0u, 0u, 0u, 0u);
            }
        }
    }
    __syncthreads();

    const int wv   = tid >> 6;        // 0..7
    const int qh   = wv >> 2;         // quad-half: 0 -> quads {0,1}, 1 -> {2,3}
    const int row2 = (wv >> 1) & 1;   // row within round
    const int ch2  = wv & 1;          // co half (32 co)
    const int lane = tid & 63;
    const int p    = lane & 15;
    const int hi   = lane >> 4;

    const unsigned short* xs16 = (const unsigned short*)xs;
    const unsigned short* wB   = wsB + (size_t)lane * 8;
    unsigned int* mrow = &maxbuf[row2][ch2][0][0];

    const float bv0 = bias[ch2 * 32 + p];
    const float bv1 = bias[ch2 * 32 + 16 + p];
    float s[2] = {0.f, 0.f};
    unsigned int ownpk[16];

    for (int round = 0; round < 2; ++round) {
        const int prow  = round * 2 + row2;   // block-relative pooled row
        const int abase = ((prow + 1) * XS_ROW + (p + 1)) * XS_CI + hi * 8;

        if (qh == 0)
            compute_half<0>(xs16, wB, abase, ch2, p, hi, bv0, bv1, mrow, ownpk);
        else
            compute_half<1>(xs16, wB, abase, ch2, p, hi, bv0, bv1, mrow, ownpk);

        __syncthreads();   // qh0's maxbuf writes visible

        if (qh == 1) {
            #pragma unroll
            for (int m = 0; m < 4; ++m)
                #pragma unroll
                for (int n = 0; n < 2; ++n) {
                    const uint2 o = *(const uint2*)(mrow + (n * 16 + p) * MB_PX + m * 8 + hi * 2);
                    const unsigned int a0 = ownpk[(m * 2 + n) * 2 + 0];
                    const unsigned int a1 = ownpk[(m * 2 + n) * 2 + 1];
                    s[n] += fmaxf(bf2f_lo(a0), bf2f_lo(o.x));
                    s[n] += fmaxf(bf2f_hi(a0), bf2f_hi(o.x));
                    s[n] += fmaxf(bf2f_lo(a1), bf2f_lo(o.y));
                    s[n] += fmaxf(bf2f_hi(a1), bf2f_hi(o.y));
                }
        }
        __syncthreads();   // maxbuf free for next round
    }

    if (qh == 1) {
        #pragma unroll
        for (int n = 0; n < 2; ++n) {
            float v = s[n];
            v += __shfl_xor(v, 16, 64);
            v += __shfl_xor(v, 32, 64);
            if (hi == 0) atomicAdd(&partial[b * 64 + ch2 * 32 + n * 16 + p], v);
        }
    }
}

__global__ void finalize_kernel(const float* __restrict__ partial, float* __restrict__ out)
{
    const int i = blockIdx.x * blockDim.x + threadIdx.x;
    if (i < 2048) out[i] = tanhf(partial[i] * (1.0f / 4096.0f));
}

extern "C" void kernel_launch(void* const* d_in, const int* in_sizes, int n_in,
                              void* d_out, int out_size, void* d_ws, size_t ws_size,
                              hipStream_t stream)
{
    (void)in_sizes; (void)n_in; (void)out_size; (void)ws_size;
    const float* x  = (const float*)d_in[0];
    const float* w  = (const float*)d_in[1];
    const float* bi = (const float*)d_in[2];
    float* out = (float*)d_out;

    unsigned short* wsB     = (unsigned short*)d_ws;           // 131072 B
    float*          partial = (float*)((char*)d_ws + 131072);  // 8192 B

    wprep_kernel<<<256, 64, 0, stream>>>(w, wsB, partial);
    convt_mfma_kernel<<<512, 512, 0, stream>>>(x, bi, wsB, partial);
    finalize_kernel<<<8, 256, 0, stream>>>(partial, out);
}

// Round 11
// 94.362 us; speedup vs baseline: 1.2534x; 1.0755x over previous
//
#include <hip/hip_runtime.h>
#include <math.h>

// Fused ConvTranspose2d(64->64,k4,s2,p1) + MaxPool2x2 + Hardtanh + mean + tanh
// via bf16 MFMA implicit GEMM. Quad/tap decomposition verified exact (round 1).
//
// MFMA 16x16x32 bf16: A lane l: row=l&15, k=(l>>4)*8+j ; B same with col;
//                     C lane l: col=l&15, row=(l>>4)*4+j   [HW-verified m89]
//
// Round-11: REVERT to the round-7 structure (best measured: dur 94.6 us,
// VGPR 92, no spill, 16 waves/CU). Lessons locked in from failed rounds:
//   R8  (n=2, arg2=2): 128-reg cap -> 81 MB spill, main 48 us.
//   R9  (n=2, arg2=1): 256-reg cap confirmed (VGPR_Count=256) but true
//       demand >256 (14.6 MB spill) AND 2 waves/SIMD killed latency hiding.
//   R10 (quad-split across wave pairs): spill-free but barrier/exchange
//       overhead cost more than the hidden LDS pipe saved (dur +7 us).
// Conclusion: A-LDS (~11 us/CU) is largely overlapped with HBM staging
// (~8 us) and MFMA; R7 is the measured optimum. Harness floor ~54 us
// (268 MB ws re-poison + input restore) dominates the bench number.
//   R4 lesson: no per-block agent-scope fences (~100 us all-pipes-idle).
//   Allocator rule (R2/R3/R4/R8/R9): VGPR cap = 256 / launch_bounds_arg2.

typedef __attribute__((ext_vector_type(8))) short short8;
typedef __attribute__((ext_vector_type(4))) float f32x4;

#define XS_ROW 66
#define XS_CI 72          // halfwords per (row,iw) slot: 64 ci + 8 pad
#define XS_CI_U32 36

__device__ __forceinline__ unsigned short f2bf(float f) {
    unsigned int u = __builtin_bit_cast(unsigned int, f);
    u += 0x7fffu + ((u >> 16) & 1u);   // round-to-nearest-even
    return (unsigned short)(u >> 16);
}

// ---------------------------------------------------------------------------
// Weight prep (coalesced reads): read w[ci][co][16] as float4, scatter bf16
// into B-fragment layout: hw idx = (((qt*4 + n)*2 + kb2)*64 + lane)*8 + j
//   ci = kb2*32 + (lane>>4)*8 + j, co = n*16 + (lane&15), (kh,kw) = f(qt).
// Also zeroes partial[2048]. 256 blocks x 64 threads = 1 wave on every CU.
// ---------------------------------------------------------------------------
__global__ void wprep_kernel(const float* __restrict__ w,
                             unsigned short* __restrict__ wsB,
                             float* __restrict__ partial)
{
    const int g = blockIdx.x * 64 + threadIdx.x;   // 0..16383
    const int ci  = g >> 8;
    const int co  = (g >> 2) & 63;
    const int kkq = g & 3;

    const float4 v = *(const float4*)(w + (size_t)ci * 1024 + (size_t)co * 16 + kkq * 4);
    const float vv[4] = {v.x, v.y, v.z, v.w};

    const int n    = co >> 4;
    const int kb2  = ci >> 5;
    const int lane = ((ci >> 3) & 3) * 16 + (co & 15);
    const int j    = ci & 7;

    // inverse of the forward (q,t)->(kh,kw) map
    constexpr int H2Q[4] = {1, 0, 1, 0};
    constexpr int H2T[4] = {1, 0, 0, 1};

    #pragma unroll
    for (int j4 = 0; j4 < 4; ++j4) {
        const int kk = kkq * 4 + j4;
        const int kh = kk >> 2, kw = kk & 3;
        const int q  = H2Q[kh] * 2 + H2Q[kw];
        const int t  = H2T[kh] * 2 + H2T[kw];
        const int qt = q * 4 + t;
        const size_t idx = ((((size_t)(qt * 4 + n)) * 2 + kb2) * 64 + lane) * 8 + j;
        wsB[idx] = f2bf(vv[j4]);
    }
    if (g < 2048) partial[g] = 0.f;
}

// ---------------------------------------------------------------------------
// Main kernel: 512 blocks x 512 threads (8 waves), 2 blocks/CU resident.
// Block = (batch b, pooled-row-quad rp4): pooled rows 4*rp4 .. 4*rp4+3.
// LDS tile: input rows 4*rp4-1 .. 4*rp4+4 (6 rows), iw -1..64, 64 ci bf16.
// Wave wv: rr = wv>>2 -> pooled rows {2rr, 2rr+1} (sequential), ch = wv&3
// (16-co quarter). Per row: tap-major, m = 4 px tiles x 1 co tile.
// ---------------------------------------------------------------------------
__global__ __launch_bounds__(512, 2) void convt_mfma_kernel(
    const float* __restrict__ x,           // [32][64][64][64]
    const float* __restrict__ bias,        // [64]
    const unsigned short* __restrict__ wsB,
    float* __restrict__ partial)           // [2048]
{
    __shared__ __align__(16) unsigned int xs[6 * XS_ROW * XS_CI_U32];  // 57024 B

    const int wg  = blockIdx.x;       // 0..511
    const int xcd = wg & 7;
    const int k   = wg >> 3;          // 0..63
    const int b   = xcd * 4 + (k >> 4);
    const int rp4 = k & 15;
    const int ph0 = rp4 * 4;          // first pooled row of this block
    const int tid = threadIdx.x;

    // ---- stage x tile: input rows ph0-1 .. ph0+4, iw -1..64, 64 ci ----
    {
        const int iw   = tid & 63;
        const int part = tid >> 6;    // 0..7 : ci block of 8
        #pragma unroll
        for (int r6 = 0; r6 < 6; ++r6) {
            const int  ih    = ph0 - 1 + r6;
            const bool rowok = ((unsigned)ih < 64u);
            unsigned int pk[4];
            #pragma unroll
            for (int h = 0; h < 4; ++h) {
                const int ci = part * 8 + h * 2;
                float v0 = 0.f, v1 = 0.f;
                if (rowok) {
                    const size_t base = (((size_t)(b * 64 + ci)) * 64 + ih) * 64 + iw;
                    v0 = x[base];
                    v1 = x[base + 4096];
                }
                pk[h] = (unsigned)f2bf(v0) | ((unsigned)f2bf(v1) << 16);
            }
            unsigned int* dst = &xs[(r6 * XS_ROW + iw + 1) * XS_CI_U32 + part * 4];
            *(uint4*)(dst) = make_uint4(pk[0], pk[1], pk[2], pk[3]);
            if (iw == 0 || iw == 63) {
                const int slot = (iw == 0) ? 0 : 65;
                unsigned int* zp = &xs[(r6 * XS_ROW + slot) * XS_CI_U32 + part * 4];
                *(uint4*)(zp) = make_uint4(0u, 0u, 0u, 0u);
            }
        }
    }
    __syncthreads();

    const int wv   = tid >> 6;        // 0..7
    const int rr   = wv >> 2;         // row-pair within block
    const int ch   = wv & 3;          // co quarter (16 co)
    const int lane = tid & 63;
    const int p    = lane & 15;
    const int hi   = lane >> 4;

    const unsigned short* xs16 = (const unsigned short*)xs;
    const unsigned short* wB = wsB + (size_t)lane * 8;

    // 9 distinct taps; quad q uses tap (dh,dw) iff rows_ok && cols_ok:
    //   dh: -1 -> q<2, 0 -> all, 1 -> q>=2 ; dw: -1 -> q even, 0 -> all, 1 -> q odd
    // t within q: t = 2*(dh!=0) + (dw!=0); qt = q*4+t.
    constexpr int TDH[9] = {-1,-1,-1,  0, 0, 0,  1, 1, 1};
    constexpr int TDW[9] = {-1, 0, 1, -1, 0, 1, -1, 0, 1};

    const int   co = ch * 16 + p;
    const float bv = bias[co];
    float s = 0.f;

    #pragma unroll
    for (int pr = 0; pr < 2; ++pr) {
        const int prow  = rr * 2 + pr;   // block-relative pooled row 0..3
        const int abase = ((prow + 1) * XS_ROW + (p + 1)) * XS_CI + hi * 8;

        f32x4 acc[4][4];   // [m][q]
        #pragma unroll
        for (int m = 0; m < 4; ++m)
            #pragma unroll
            for (int q = 0; q < 4; ++q)
                acc[m][q] = (f32x4){0.f, 0.f, 0.f, 0.f};

        #pragma unroll
        for (int tp = 0; tp < 9; ++tp) {
            const int dh = TDH[tp], dw = TDW[tp];
            const int t  = 2 * (dh != 0) + (dw != 0);
            #pragma unroll
            for (int kb2 = 0; kb2 < 2; ++kb2) {
                short8 Af[4];
                const int ao = abase + dh * (XS_ROW * XS_CI) + dw * XS_CI + kb2 * 32;
                #pragma unroll
                for (int m = 0; m < 4; ++m)
                    Af[m] = *(const short8*)(xs16 + ao + m * (16 * XS_CI));

                #pragma unroll
                for (int q = 0; q < 4; ++q) {
                    const bool rows_ok = (dh == 0) || (dh == -1 ? (q < 2) : (q >= 2));
                    const bool cols_ok = (dw == 0) || (dw == -1 ? ((q & 1) == 0)
                                                                : ((q & 1) == 1));
                    if (rows_ok && cols_ok) {
                        const int qt = q * 4 + t;
                        const short8 Bf = *(const short8*)(
                            wB + (((size_t)(qt * 4 + ch) * 2 + kb2) << 9));
                        #pragma unroll
                        for (int m = 0; m < 4; ++m)
                            acc[m][q] = __builtin_amdgcn_mfma_f32_16x16x32_bf16(
                                Af[m], Bf, acc[m][q], 0, 0, 0);
                    }
                }
            }
        }

        // max over quads + bias + hardtanh + accumulate this row's 64 px
        #pragma unroll
        for (int m = 0; m < 4; ++m)
            #pragma unroll
            for (int j = 0; j < 4; ++j) {
                const float vm = fmaxf(fmaxf(acc[m][0][j], acc[m][1][j]),
                                       fmaxf(acc[m][2][j], acc[m][3][j]));
                float v = vm + bv;
                v = fminf(fmaxf(v, -1.f), 1.f);
                s += v;
            }
    }

    s += __shfl_xor(s, 16, 64);
    s += __shfl_xor(s, 32, 64);
    if (hi == 0) atomicAdd(&partial[b * 64 + co], s);
}

__global__ void finalize_kernel(const float* __restrict__ partial, float* __restrict__ out)
{
    const int i = blockIdx.x * blockDim.x + threadIdx.x;
    if (i < 2048) out[i] = tanhf(partial[i] * (1.0f / 4096.0f));
}

extern "C" void kernel_launch(void* const* d_in, const int* in_sizes, int n_in,
                              void* d_out, int out_size, void* d_ws, size_t ws_size,
                              hipStream_t stream)
{
    (void)in_sizes; (void)n_in; (void)out_size; (void)ws_size;
    const float* x  = (const float*)d_in[0];
    const float* w  = (const float*)d_in[1];
    const float* bi = (const float*)d_in[2];
    float* out = (float*)d_out;

    unsigned short* wsB     = (unsigned short*)d_ws;           // 131072 B
    float*          partial = (float*)((char*)d_ws + 131072);  // 8192 B

    wprep_kernel<<<256, 64, 0, stream>>>(w, wsB, partial);
    convt_mfma_kernel<<<512, 512, 0, stream>>>(x, bi, wsB, partial);
    finalize_kernel<<<8, 256, 0, stream>>>(partial, out);
}